// Round 12
// baseline (309.355 us; speedup 1.0000x reference)
//
#include <hip/hip_runtime.h>
#include <hip/hip_bf16.h>

#define N_NODES 100000
#define N_EDGES 1600000
#define D       64
#define N_RELS  200
#define LEAKY   0.01f
// fine buckets of 128 nodes; z (d&127) packed into payl.y bits 25..31
#define NBUCK      782
#define BUCK_SHIFT 7
#define BUCK_MASK  127
#define NPB        128
#define CAP        3072            // LDS record capacity; mean 2048, sigma~45 -> 22 sigma
#define BIN_CHUNK  2048
#define NBIN       ((N_EDGES + BIN_CHUNK - 1) / BIN_CHUNK)   // 782
// pad global atomic counters to one per 64B cache line: 782 blocks x ~719 buckets
// of device-scope atomics previously hit 49 dense lines -> ~11.5K serialized RMWs
// per line (the hidden ~tens-of-us in proj phase C and k_bin, and the 30.6 ms
// k_bin outlier). Padded: 782 lines, ~719 RMWs each, parallel across XCD L2s.
#define CPAD       16

typedef __hip_bfloat16 bf16;

__device__ __forceinline__ float b2f(bf16 x) { return __bfloat162float(x); }
__device__ __forceinline__ bf16  f2b(float x) { return __float2bfloat16(x); }

// dtype-dispatching float load: bf==1 -> storage is bf16, else f32 (probe says f32 here)
__device__ __forceinline__ float ldf(const void* p, long i, int bf) {
    return bf ? __bfloat162float(((const bf16*)p)[i]) : ((const float*)p)[i];
}
__device__ __forceinline__ int probe_bf(const void* delta) {
    return ((const unsigned short*)delta)[0] == 0x3F80 ? 1 : 0;
}

// uniform-index lane broadcast via v_readlane (result lands in SGPR)
__device__ __forceinline__ int rl_i(int v, int l) {
    return __builtin_amdgcn_readlane(v, l);
}
__device__ __forceinline__ float rl_f(float v, int l) {
    return __int_as_float(__builtin_amdgcn_readlane(__float_as_int(v), l));
}

// K1: node proj (hWb, s_src, s_dst) + rel proj (relW f32, s_rel) + coarse dst histogram.
// EXACT round-8 phase A/B (63.4 us measured): 8 nodes/iter at (512,4), grid 782.
// DO NOT merge other matmul phases (round-10 A2 merge spilled: WRITE 27->146 MB).
// Phase C flush now targets line-padded bcnt.
__global__ __launch_bounds__(512, 4) void k_fused_proj(const void* __restrict__ h,
                                                       const void* __restrict__ wn,
                                                       const void* __restrict__ attn,
                                                       const void* __restrict__ delta,
                                                       const void* __restrict__ rel_emb,
                                                       const int* __restrict__ dst,
                                                       bf16* __restrict__ hWb,
                                                       float* __restrict__ s_src,
                                                       float* __restrict__ s_dst,
                                                       float* __restrict__ relW,
                                                       float* __restrict__ s_rel,
                                                       int* __restrict__ bcnt) {
    __shared__ int bh[NBUCK];
    const int bf = probe_bf(delta);
    const int wave = threadIdx.x >> 6;
    const int lane = threadIdx.x & 63;
    const int gw = blockIdx.x * 8 + wave;
    const int nwaves = gridDim.x * 8;
    float wreg[D];
    #pragma unroll
    for (int k = 0; k < D; k++) wreg[k] = ldf(wn, (long)k * D + lane, bf);
    const float a1 = ldf(attn, lane, bf);
    const float a2 = ldf(attn, D + lane, bf);
    // phase A: 8 nodes per iteration (N_NODES % 8 == 0)
    for (int base = gw * 8; base < N_NODES; base += nwaves * 8) {
        float hv[8], acc[8];
        #pragma unroll
        for (int j = 0; j < 8; j++) {
            hv[j] = ldf(h, (long)(base + j) * D + lane, bf);
            acc[j] = 0.f;
        }
        #pragma unroll
        for (int j = 0; j < 8; j++) {
            float p1 = hv[j] * a1, p2 = hv[j] * a2;
            #pragma unroll
            for (int off = 32; off; off >>= 1) { p1 += __shfl_xor(p1, off); p2 += __shfl_xor(p2, off); }
            if (lane == 0) { s_src[base + j] = p1; s_dst[base + j] = p2; }
        }
        #pragma unroll
        for (int k = 0; k < D; k++) {
            float w = wreg[k];
            #pragma unroll
            for (int j = 0; j < 8; j++) acc[j] += rl_f(hv[j], k) * w;
        }
        #pragma unroll
        for (int j = 0; j < 8; j++) hWb[(long)(base + j) * D + lane] = f2b(acc[j]);
    }
    // phase B: relations (200 waves; L2-hot, tiny)
    const float a3 = ldf(attn, 2 * D + lane, bf);
    for (int r = gw; r < N_RELS; r += nwaves) {
        float rv = ldf(rel_emb, (long)r * D + lane, bf);
        float p3 = rv * a3;
        #pragma unroll
        for (int off = 32; off; off >>= 1) p3 += __shfl_xor(p3, off);
        if (lane == 0) s_rel[r] = p3;
        float acc = 0.f;
        #pragma unroll
        for (int k = 0; k < D; k++) {
            acc += rl_f(rv, k) * ldf(wn, (long)(D + k) * D + lane, bf);
        }
        relW[r * D + lane] = acc;
    }
    // phase C: coarse (dst>>7) histogram, LDS-aggregated; flush to line-padded bcnt
    for (int t = threadIdx.x; t < NBUCK; t += 512) bh[t] = 0;
    __syncthreads();
    for (int t = blockIdx.x * 512 + threadIdx.x; t < N_EDGES; t += gridDim.x * 512)
        atomicAdd(&bh[dst[t] >> BUCK_SHIFT], 1);
    __syncthreads();
    for (int t = threadIdx.x; t < NBUCK; t += 512) {
        int v = bh[t];
        if (v) atomicAdd(&bcnt[t << 4], v);    // one counter per 64B line
    }
}

// exclusive scan of the 782 bucket counts (line-padded source); primes line-padded
// bcursor and dense bbase
__global__ __launch_bounds__(1024) void k_bscan(const int* __restrict__ bcnt,
                                                int* __restrict__ bbase,
                                                int* __restrict__ bcursor) {
    __shared__ int s[1024];
    const int tid = threadIdx.x;
    int v = (tid < NBUCK) ? bcnt[tid << 4] : 0;
    s[tid] = v;
    __syncthreads();
    for (int off = 1; off < 1024; off <<= 1) {
        int t = (tid >= off) ? s[tid - off] : 0;
        __syncthreads();
        s[tid] += t;
        __syncthreads();
    }
    if (tid < NBUCK) {
        int e = s[tid] - v;
        bbase[tid] = e;
        bcursor[tid << 4] = e;                 // one cursor per 64B line
    }
    if (tid == 1023) bbase[NBUCK] = s[1023];   // == N_EDGES
}

// Pass B: rank edges into 782 fine buckets via LDS atomics, then scatter
// {ex, src | rel<<17 | z<<25} (8B) into per-(block,bucket) runs.
// 782 blocks at (512,6) -> 3 blocks/CU resident. Cursor atomics line-padded.
__global__ __launch_bounds__(512, 6) void k_bin(const float* __restrict__ s_src,
                                                const float* __restrict__ s_dst,
                                                const float* __restrict__ s_rel,
                                                const void* __restrict__ etime,
                                                const void* __restrict__ delta,
                                                const int* __restrict__ src,
                                                const int* __restrict__ dst,
                                                const int* __restrict__ etype,
                                                int* __restrict__ bcursor,
                                                int2* __restrict__ payl) {
    __shared__ int lh[NBUCK];
    __shared__ int gbase[NBUCK];
    const int bf = probe_bf(delta);
    const float df = ldf(delta, 0, bf);
    const int tid = threadIdx.x;
    const int base = blockIdx.x * BIN_CHUNK;
    for (int t = tid; t < NBUCK; t += 512) lh[t] = 0;
    __syncthreads();
    int2 rc[4];
    int rk[4], bk[4];
    #pragma unroll
    for (int j = 0; j < 4; j++) {
        int e = base + j * 512 + tid;
        bk[j] = -1;
        if (e < N_EDGES) {
            int s = src[e], d = dst[e], r = etype[e];
            float scv = s_src[s] + s_dst[d] + s_rel[r];
            float lre = scv > 0.f ? scv : LEAKY * scv;
            float score = (-ldf(etime, e, bf) * df) * lre;
            rc[j].x = __float_as_int(__expf(score));
            rc[j].y = s | (r << 17) | ((d & BUCK_MASK) << 25);  // 17+8+7 = 32 bits
            int b = d >> BUCK_SHIFT;
            bk[j] = b;
            rk[j] = atomicAdd(&lh[b], 1);
        }
    }
    __syncthreads();
    for (int t = tid; t < NBUCK; t += 512) {
        int v = lh[t];
        if (v) gbase[t] = atomicAdd(&bcursor[t << 4], v);   // one cursor per line
    }
    __syncthreads();
    #pragma unroll
    for (int j = 0; j < 4; j++) {
        if (bk[j] >= 0) payl[gbase[bk[j]] + rk[j]] = rc[j];
    }
}

// Dense loop-term: L[i] = h[i] @ loopW for ALL nodes — EXACT round-8 standalone form
// (8 nodes/iter, (512,4), grid 782; ~128 VGPR, no spill). deg==0 nodes (P=e^-16)
// corrected in k_bagg's cold branch.
__global__ __launch_bounds__(512, 4) void k_loop(const void* __restrict__ h,
                                                 const void* __restrict__ loopW,
                                                 const void* __restrict__ delta,
                                                 float* __restrict__ L) {
    const int bf = probe_bf(delta);
    const int wave = threadIdx.x >> 6;
    const int lane = threadIdx.x & 63;
    const int gw = blockIdx.x * 8 + wave;
    const int nwaves = gridDim.x * 8;
    float wreg[D];
    #pragma unroll
    for (int k = 0; k < D; k++) wreg[k] = ldf(loopW, (long)k * D + lane, bf);
    for (int base = gw * 8; base < N_NODES; base += nwaves * 8) {
        float hv[8], acc[8];
        #pragma unroll
        for (int j = 0; j < 8; j++) {
            hv[j] = ldf(h, (long)(base + j) * D + lane, bf);
            acc[j] = 0.f;
        }
        #pragma unroll
        for (int k = 0; k < D; k++) {
            float w = wreg[k];
            #pragma unroll
            for (int j = 0; j < 8; j++) acc[j] += rl_f(hv[j], k) * w;
        }
        #pragma unroll
        for (int j = 0; j < 8; j++) L[(long)(base + j) * D + lane] = acc[j];
    }
}

// Fused bucket-sort + aggregate: one block per 128-node bucket. Sort the bucket's
// edge run into LDS, then aggregate directly from LDS with group-broadcast reads.
// (512,6): LDS 25.6KB*3=77KB fits, VGPR cap 85 -> 3 blocks/CU resident.
__global__ __launch_bounds__(512, 6) void k_bagg(const int2* __restrict__ payl,
                                                 const int* __restrict__ bbase,
                                                 const bf16* __restrict__ hWb,
                                                 const float* __restrict__ relW,
                                                 const void* __restrict__ h,
                                                 const void* __restrict__ evolveW,
                                                 const float* __restrict__ L,
                                                 const void* __restrict__ delta,
                                                 float* __restrict__ out) {
    __shared__ int2 recs[CAP];              // 24 KB
    __shared__ int cnt[NPB], off[NPB], fc[NPB];
    const int bf = probe_bf(delta);
    const int tid = threadIdx.x;
    const int b = blockIdx.x;
    const int n0 = b << BUCK_SHIFT;
    const int s0 = bbase[b], s1 = bbase[b + 1];
    const int run = s1 - s0;
    if (tid < NPB) { cnt[tid] = 0; fc[tid] = 0; }
    __syncthreads();
    // fine histogram over the run
    for (int i = tid; i < run; i += 512)
        atomicAdd(&cnt[((unsigned)payl[s0 + i].y) >> 25], 1);
    __syncthreads();
    if (tid < NPB) off[tid] = cnt[tid];
    __syncthreads();
    for (int o = 1; o < NPB; o <<= 1) {
        int t = 0;
        if (tid < NPB && tid >= o) t = off[tid - o];
        __syncthreads();
        if (tid < NPB) off[tid] += t;
        __syncthreads();
    }
    if (tid < NPB) off[tid] -= cnt[tid];    // exclusive offsets
    __syncthreads();
    // scatter into LDS (payl re-read is L2-hot)
    for (int i = tid; i < run; i += 512) {
        int2 r = payl[s0 + i];
        int z = ((unsigned)r.y) >> 25;
        int pos = off[z] + atomicAdd(&fc[z], 1);
        if (pos < CAP) recs[pos] = r;
    }
    __syncthreads();
    // aggregation: 8 waves x 16 nodes, 4-group x 16-lane x 4-channel gather
    const int wave = tid >> 6, lane = tid & 63;
    const int grp = lane >> 4, sub = lane & 15;
    const unsigned sub8 = (unsigned)sub << 3;
    const unsigned sub16 = (unsigned)sub << 4;
    for (int t = 0; t < 16; ++t) {
        const int z = wave * 16 + t;
        const int i = n0 + z;
        if (i >= N_NODES) break;
        const int d = cnt[z], o = off[z];
        if (d > 0) {
            float ax = 0.f, ay = 0.f, az = 0.f, aw = 0.f, ws = 0.f;
            if (o + d <= CAP) {
                #pragma unroll 2
                for (int j = 0; j < d; j += 4) {
                    int jj = j + grp;
                    int2 rr = (jj < d) ? recs[o + jj] : make_int2(0, 0);  // LDS broadcast in group
                    float w = __int_as_float(rr.x);                        // 0.0 when masked
                    int p = rr.y;
                    unsigned hoff = ((unsigned)(p & 0x1FFFF) << 7) + sub8;
                    unsigned roff = ((((unsigned)p >> 17) & 0xFFu) << 8) + sub16;
                    uint2  hw = *(const uint2*) ((const char*)hWb  + hoff);
                    float4 rw = *(const float4*)((const char*)relW + roff);
                    float f0 = __uint_as_float(hw.x << 16);
                    float f1 = __uint_as_float(hw.x & 0xFFFF0000u);
                    float f2 = __uint_as_float(hw.y << 16);
                    float f3 = __uint_as_float(hw.y & 0xFFFF0000u);
                    ax += w * (f0 + rw.x);
                    ay += w * (f1 + rw.y);
                    az += w * (f2 + rw.z);
                    aw += w * (f3 + rw.w);
                    ws += w;
                }
            } else {
                // ~never taken: z-filtered rescan of the global run, same fold shape
                for (int j = 0; j < run; j += 4) {
                    int jj = j + grp;
                    if (jj < run) {
                        int2 rr = payl[s0 + jj];
                        if ((int)(((unsigned)rr.y) >> 25) == z) {
                            float w = __int_as_float(rr.x);
                            int p = rr.y;
                            unsigned hoff = ((unsigned)(p & 0x1FFFF) << 7) + sub8;
                            unsigned roff = ((((unsigned)p >> 17) & 0xFFu) << 8) + sub16;
                            uint2  hw = *(const uint2*) ((const char*)hWb  + hoff);
                            float4 rw = *(const float4*)((const char*)relW + roff);
                            ax += w * (__uint_as_float(hw.x << 16) + rw.x);
                            ay += w * (__uint_as_float(hw.x & 0xFFFF0000u) + rw.y);
                            az += w * (__uint_as_float(hw.y << 16) + rw.z);
                            aw += w * (__uint_as_float(hw.y & 0xFFFF0000u) + rw.w);
                            ws += w;
                        }
                    }
                }
            }
            // fold the 4 group-partials (group-uniform ws folds identically)
            ax += __shfl_xor(ax, 16); ax += __shfl_xor(ax, 32);
            ay += __shfl_xor(ay, 16); ay += __shfl_xor(ay, 32);
            az += __shfl_xor(az, 16); az += __shfl_xor(az, 32);
            aw += __shfl_xor(aw, 16); aw += __shfl_xor(aw, 32);
            ws += __shfl_xor(ws, 16); ws += __shfl_xor(ws, 32);
            if (grp == 0) {
                const float inv = 1.f / ws;     // ws > 0: every stored ex = exp(finite) > 0
                const float4 l4 = *(const float4*)(L + (long)i * D + sub * 4);
                float4 r;
                r.x = ax * inv + l4.x;
                r.y = ay * inv + l4.y;
                r.z = az * inv + l4.z;
                r.w = aw * inv + l4.w;
                *(float4*)(out + (long)i * D + sub * 4) = r;
            }
        } else {
            // cold: deg==0 (P=e^-16). out = h + h @ evolveW; evolveW is L2-hot.
            float hv = ldf(h, (long)i * D + lane, bf);
            float acc = hv;
            for (int k = 0; k < D; k++)
                acc += rl_f(hv, k) * ldf(evolveW, (long)k * D + lane, bf);
            out[(long)i * D + lane] = acc;
        }
    }
}

// safe diagnostic fallback
__global__ __launch_bounds__(256) void k_fallback(float* __restrict__ out) {
    int t = blockIdx.x * blockDim.x + threadIdx.x;
    if (t < N_NODES * D) out[t] = 0.f;
}

extern "C" void kernel_launch(void* const* d_in, const int* in_sizes, int n_in,
                              void* d_out, int out_size, void* d_ws, size_t ws_size,
                              hipStream_t stream) {
    const void* h       = d_in[0];
    const void* rel_emb = d_in[1];
    const void* wn      = d_in[2];
    const void* attn    = d_in[3];
    const void* delta   = d_in[4];
    const void* loopW   = d_in[5];
    const void* evolveW = d_in[6];
    const void* etime   = d_in[7];
    const int*  src     = (const int*)d_in[8];
    const int*  dst     = (const int*)d_in[9];
    const int*  etype   = (const int*)d_in[10];
    float* out = (float*)d_out;

    char* ws = (char*)d_ws;
    size_t off = 0;
    auto alloc = [&](size_t bytes) -> void* {
        off = (off + 255) & ~(size_t)255;
        void* p = ws + off;
        off += bytes;
        return p;
    };
    int2*  payl    = (int2*) alloc((size_t)N_EDGES * 8);         // 12.8 MB
    float* L       = (float*)alloc((size_t)N_NODES * D * 4);     // 25.6 MB
    bf16*  hWb     = (bf16*) alloc((size_t)N_NODES * D * 2);     // 12.8 MB
    float* relW    = (float*)alloc((size_t)N_RELS * D * 4);      // 51.2 KB
    float* s_src   = (float*)alloc((size_t)N_NODES * 4);         //  0.4 MB
    float* s_dst   = (float*)alloc((size_t)N_NODES * 4);         //  0.4 MB
    float* s_rel   = (float*)alloc((size_t)N_RELS * 4);          //  0.8 KB
    int*   bcnt    = (int*)  alloc((size_t)NBUCK * CPAD * 4);    // 50 KB (line-padded)
    int*   bbase   = (int*)  alloc((size_t)(NBUCK + 1) * 4);
    int*   bcursor = (int*)  alloc((size_t)NBUCK * CPAD * 4);    // 50 KB (line-padded)
    // total ~52.2 MB (< proven-available 52.9 MB from rounds 1-11)

    if (ws_size < off) {
        k_fallback<<<(N_NODES * D + 255) / 256, 256, 0, stream>>>(out);
        return;
    }

    hipMemsetAsync(bcnt, 0, (size_t)NBUCK * CPAD * 4, stream);
    k_fused_proj<<<782, 512, 0, stream>>>(h, wn, attn, delta, rel_emb, dst,
                                          hWb, s_src, s_dst, relW, s_rel, bcnt);
    k_bscan<<<1, 1024, 0, stream>>>(bcnt, bbase, bcursor);
    k_bin<<<NBIN, 512, 0, stream>>>(s_src, s_dst, s_rel, etime, delta,
                                    src, dst, etype, bcursor, payl);
    k_loop<<<782, 512, 0, stream>>>(h, loopW, delta, L);
    k_bagg<<<NBUCK, 512, 0, stream>>>(payl, bbase, hWb, relW, h, evolveW, L, delta, out);
}

// Round 13
// 293.161 us; speedup vs baseline: 1.0552x; 1.0552x over previous
//
#include <hip/hip_runtime.h>
#include <hip/hip_bf16.h>

#define N_NODES 100000
#define N_EDGES 1600000
#define D       64
#define N_RELS  200
#define LEAKY   0.01f
// fine buckets of 128 nodes; z (d&127) packed into payl.y bits 25..31
#define NBUCK      782
#define BUCK_SHIFT 7
#define BUCK_MASK  127
#define NPB        128
#define CAP        3072            // LDS record capacity; mean 2048, sigma~45 -> 22 sigma
#define BIN_CHUNK  2048
#define NBIN       ((N_EDGES + BIN_CHUNK - 1) / BIN_CHUNK)   // 782
// NOTE (round-12 post-mortem): keep bcnt/bcursor DENSE. Line-padding the atomic
// targets (one counter per 64B line) broke wave-level atomic coalescing at the L2
// interface: 64 atomics/wave -> 64 line transactions + writebacks (WRITE +15.3 MB,
// proj 63.5->72 us). Dense contiguous counters let the L2 pipeline same-line RMWs.

typedef __hip_bfloat16 bf16;

__device__ __forceinline__ float b2f(bf16 x) { return __bfloat162float(x); }
__device__ __forceinline__ bf16  f2b(float x) { return __float2bfloat16(x); }

// dtype-dispatching float load: bf==1 -> storage is bf16, else f32 (probe says f32 here)
__device__ __forceinline__ float ldf(const void* p, long i, int bf) {
    return bf ? __bfloat162float(((const bf16*)p)[i]) : ((const float*)p)[i];
}
__device__ __forceinline__ int probe_bf(const void* delta) {
    return ((const unsigned short*)delta)[0] == 0x3F80 ? 1 : 0;
}

// uniform-index lane broadcast via v_readlane (result lands in SGPR)
__device__ __forceinline__ int rl_i(int v, int l) {
    return __builtin_amdgcn_readlane(v, l);
}
__device__ __forceinline__ float rl_f(float v, int l) {
    return __int_as_float(__builtin_amdgcn_readlane(__float_as_int(v), l));
}

// K1: node proj (hWb, s_src, s_dst) + rel proj (relW f32, s_rel) + coarse dst histogram.
// EXACT round-8 form: 63.4 us measured. 8 nodes/iter at (512,4), grid 782 ->
// phase A exactly 2.0 iters/wave. DO NOT merge other matmul phases in here:
// round-10's A2 merge (wreg reload + second hv/acc phase) spilled -> WRITE 27->146 MB,
// 63->165 us. These register-resident-W phases are spill-free ONLY standalone.
__global__ __launch_bounds__(512, 4) void k_fused_proj(const void* __restrict__ h,
                                                       const void* __restrict__ wn,
                                                       const void* __restrict__ attn,
                                                       const void* __restrict__ delta,
                                                       const void* __restrict__ rel_emb,
                                                       const int* __restrict__ dst,
                                                       bf16* __restrict__ hWb,
                                                       float* __restrict__ s_src,
                                                       float* __restrict__ s_dst,
                                                       float* __restrict__ relW,
                                                       float* __restrict__ s_rel,
                                                       int* __restrict__ bcnt) {
    __shared__ int bh[NBUCK];
    const int bf = probe_bf(delta);
    const int wave = threadIdx.x >> 6;
    const int lane = threadIdx.x & 63;
    const int gw = blockIdx.x * 8 + wave;
    const int nwaves = gridDim.x * 8;
    float wreg[D];
    #pragma unroll
    for (int k = 0; k < D; k++) wreg[k] = ldf(wn, (long)k * D + lane, bf);
    const float a1 = ldf(attn, lane, bf);
    const float a2 = ldf(attn, D + lane, bf);
    // phase A: 8 nodes per iteration (N_NODES % 8 == 0)
    for (int base = gw * 8; base < N_NODES; base += nwaves * 8) {
        float hv[8], acc[8];
        #pragma unroll
        for (int j = 0; j < 8; j++) {
            hv[j] = ldf(h, (long)(base + j) * D + lane, bf);
            acc[j] = 0.f;
        }
        #pragma unroll
        for (int j = 0; j < 8; j++) {
            float p1 = hv[j] * a1, p2 = hv[j] * a2;
            #pragma unroll
            for (int off = 32; off; off >>= 1) { p1 += __shfl_xor(p1, off); p2 += __shfl_xor(p2, off); }
            if (lane == 0) { s_src[base + j] = p1; s_dst[base + j] = p2; }
        }
        #pragma unroll
        for (int k = 0; k < D; k++) {
            float w = wreg[k];
            #pragma unroll
            for (int j = 0; j < 8; j++) acc[j] += rl_f(hv[j], k) * w;
        }
        #pragma unroll
        for (int j = 0; j < 8; j++) hWb[(long)(base + j) * D + lane] = f2b(acc[j]);
    }
    // phase B: relations (200 waves; L2-hot, tiny)
    const float a3 = ldf(attn, 2 * D + lane, bf);
    for (int r = gw; r < N_RELS; r += nwaves) {
        float rv = ldf(rel_emb, (long)r * D + lane, bf);
        float p3 = rv * a3;
        #pragma unroll
        for (int off = 32; off; off >>= 1) p3 += __shfl_xor(p3, off);
        if (lane == 0) s_rel[r] = p3;
        float acc = 0.f;
        #pragma unroll
        for (int k = 0; k < D; k++) {
            acc += rl_f(rv, k) * ldf(wn, (long)(D + k) * D + lane, bf);
        }
        relW[r * D + lane] = acc;
    }
    // phase C: coarse (dst>>7) histogram, LDS-aggregated; dense flush (see NOTE)
    for (int t = threadIdx.x; t < NBUCK; t += 512) bh[t] = 0;
    __syncthreads();
    for (int t = blockIdx.x * 512 + threadIdx.x; t < N_EDGES; t += gridDim.x * 512)
        atomicAdd(&bh[dst[t] >> BUCK_SHIFT], 1);
    __syncthreads();
    for (int t = threadIdx.x; t < NBUCK; t += 512) {
        int v = bh[t];
        if (v) atomicAdd(&bcnt[t], v);
    }
}

// exclusive scan of the 782 bucket counts; primes bcursor and bbase
__global__ __launch_bounds__(1024) void k_bscan(const int* __restrict__ bcnt,
                                                int* __restrict__ bbase,
                                                int* __restrict__ bcursor) {
    __shared__ int s[1024];
    const int tid = threadIdx.x;
    int v = (tid < NBUCK) ? bcnt[tid] : 0;
    s[tid] = v;
    __syncthreads();
    for (int off = 1; off < 1024; off <<= 1) {
        int t = (tid >= off) ? s[tid - off] : 0;
        __syncthreads();
        s[tid] += t;
        __syncthreads();
    }
    if (tid < NBUCK) {
        int e = s[tid] - v;
        bbase[tid] = e;
        bcursor[tid] = e;
    }
    if (tid == 1023) bbase[NBUCK] = s[1023];   // == N_EDGES
}

// Pass B: rank edges into 782 fine buckets via LDS atomics, then scatter
// {ex, src | rel<<17 | z<<25} (8B) into per-(block,bucket) runs.
// 782 blocks at (512,6) -> 3 blocks/CU resident. Dense cursor atomics (see NOTE).
__global__ __launch_bounds__(512, 6) void k_bin(const float* __restrict__ s_src,
                                                const float* __restrict__ s_dst,
                                                const float* __restrict__ s_rel,
                                                const void* __restrict__ etime,
                                                const void* __restrict__ delta,
                                                const int* __restrict__ src,
                                                const int* __restrict__ dst,
                                                const int* __restrict__ etype,
                                                int* __restrict__ bcursor,
                                                int2* __restrict__ payl) {
    __shared__ int lh[NBUCK];
    __shared__ int gbase[NBUCK];
    const int bf = probe_bf(delta);
    const float df = ldf(delta, 0, bf);
    const int tid = threadIdx.x;
    const int base = blockIdx.x * BIN_CHUNK;
    for (int t = tid; t < NBUCK; t += 512) lh[t] = 0;
    __syncthreads();
    int2 rc[4];
    int rk[4], bk[4];
    #pragma unroll
    for (int j = 0; j < 4; j++) {
        int e = base + j * 512 + tid;
        bk[j] = -1;
        if (e < N_EDGES) {
            int s = src[e], d = dst[e], r = etype[e];
            float scv = s_src[s] + s_dst[d] + s_rel[r];
            float lre = scv > 0.f ? scv : LEAKY * scv;
            float score = (-ldf(etime, e, bf) * df) * lre;
            rc[j].x = __float_as_int(__expf(score));
            rc[j].y = s | (r << 17) | ((d & BUCK_MASK) << 25);  // 17+8+7 = 32 bits
            int b = d >> BUCK_SHIFT;
            bk[j] = b;
            rk[j] = atomicAdd(&lh[b], 1);
        }
    }
    __syncthreads();
    for (int t = tid; t < NBUCK; t += 512) {
        int v = lh[t];
        if (v) gbase[t] = atomicAdd(&bcursor[t], v);
    }
    __syncthreads();
    #pragma unroll
    for (int j = 0; j < 4; j++) {
        if (bk[j] >= 0) payl[gbase[bk[j]] + rk[j]] = rc[j];
    }
}

// Dense loop-term: L[i] = h[i] @ loopW for ALL nodes — EXACT round-8 standalone form
// (8 nodes/iter, (512,4), grid 782; ~128 VGPR, no spill). deg==0 nodes (P=e^-16)
// corrected in k_bagg's cold branch.
__global__ __launch_bounds__(512, 4) void k_loop(const void* __restrict__ h,
                                                 const void* __restrict__ loopW,
                                                 const void* __restrict__ delta,
                                                 float* __restrict__ L) {
    const int bf = probe_bf(delta);
    const int wave = threadIdx.x >> 6;
    const int lane = threadIdx.x & 63;
    const int gw = blockIdx.x * 8 + wave;
    const int nwaves = gridDim.x * 8;
    float wreg[D];
    #pragma unroll
    for (int k = 0; k < D; k++) wreg[k] = ldf(loopW, (long)k * D + lane, bf);
    for (int base = gw * 8; base < N_NODES; base += nwaves * 8) {
        float hv[8], acc[8];
        #pragma unroll
        for (int j = 0; j < 8; j++) {
            hv[j] = ldf(h, (long)(base + j) * D + lane, bf);
            acc[j] = 0.f;
        }
        #pragma unroll
        for (int k = 0; k < D; k++) {
            float w = wreg[k];
            #pragma unroll
            for (int j = 0; j < 8; j++) acc[j] += rl_f(hv[j], k) * w;
        }
        #pragma unroll
        for (int j = 0; j < 8; j++) L[(long)(base + j) * D + lane] = acc[j];
    }
}

// Fused bucket-sort + aggregate: one block per 128-node bucket. Sort the bucket's
// edge run into LDS, then aggregate directly from LDS with group-broadcast reads.
// (512,6): LDS 25.6KB*3=77KB fits, VGPR cap 85 -> 3 blocks/CU resident.
__global__ __launch_bounds__(512, 6) void k_bagg(const int2* __restrict__ payl,
                                                 const int* __restrict__ bbase,
                                                 const bf16* __restrict__ hWb,
                                                 const float* __restrict__ relW,
                                                 const void* __restrict__ h,
                                                 const void* __restrict__ evolveW,
                                                 const float* __restrict__ L,
                                                 const void* __restrict__ delta,
                                                 float* __restrict__ out) {
    __shared__ int2 recs[CAP];              // 24 KB
    __shared__ int cnt[NPB], off[NPB], fc[NPB];
    const int bf = probe_bf(delta);
    const int tid = threadIdx.x;
    const int b = blockIdx.x;
    const int n0 = b << BUCK_SHIFT;
    const int s0 = bbase[b], s1 = bbase[b + 1];
    const int run = s1 - s0;
    if (tid < NPB) { cnt[tid] = 0; fc[tid] = 0; }
    __syncthreads();
    // fine histogram over the run
    for (int i = tid; i < run; i += 512)
        atomicAdd(&cnt[((unsigned)payl[s0 + i].y) >> 25], 1);
    __syncthreads();
    if (tid < NPB) off[tid] = cnt[tid];
    __syncthreads();
    for (int o = 1; o < NPB; o <<= 1) {
        int t = 0;
        if (tid < NPB && tid >= o) t = off[tid - o];
        __syncthreads();
        if (tid < NPB) off[tid] += t;
        __syncthreads();
    }
    if (tid < NPB) off[tid] -= cnt[tid];    // exclusive offsets
    __syncthreads();
    // scatter into LDS (payl re-read is L2-hot)
    for (int i = tid; i < run; i += 512) {
        int2 r = payl[s0 + i];
        int z = ((unsigned)r.y) >> 25;
        int pos = off[z] + atomicAdd(&fc[z], 1);
        if (pos < CAP) recs[pos] = r;
    }
    __syncthreads();
    // aggregation: 8 waves x 16 nodes, 4-group x 16-lane x 4-channel gather
    const int wave = tid >> 6, lane = tid & 63;
    const int grp = lane >> 4, sub = lane & 15;
    const unsigned sub8 = (unsigned)sub << 3;
    const unsigned sub16 = (unsigned)sub << 4;
    for (int t = 0; t < 16; ++t) {
        const int z = wave * 16 + t;
        const int i = n0 + z;
        if (i >= N_NODES) break;
        const int d = cnt[z], o = off[z];
        if (d > 0) {
            float ax = 0.f, ay = 0.f, az = 0.f, aw = 0.f, ws = 0.f;
            if (o + d <= CAP) {
                #pragma unroll 2
                for (int j = 0; j < d; j += 4) {
                    int jj = j + grp;
                    int2 rr = (jj < d) ? recs[o + jj] : make_int2(0, 0);  // LDS broadcast in group
                    float w = __int_as_float(rr.x);                        // 0.0 when masked
                    int p = rr.y;
                    unsigned hoff = ((unsigned)(p & 0x1FFFF) << 7) + sub8;
                    unsigned roff = ((((unsigned)p >> 17) & 0xFFu) << 8) + sub16;
                    uint2  hw = *(const uint2*) ((const char*)hWb  + hoff);
                    float4 rw = *(const float4*)((const char*)relW + roff);
                    float f0 = __uint_as_float(hw.x << 16);
                    float f1 = __uint_as_float(hw.x & 0xFFFF0000u);
                    float f2 = __uint_as_float(hw.y << 16);
                    float f3 = __uint_as_float(hw.y & 0xFFFF0000u);
                    ax += w * (f0 + rw.x);
                    ay += w * (f1 + rw.y);
                    az += w * (f2 + rw.z);
                    aw += w * (f3 + rw.w);
                    ws += w;
                }
            } else {
                // ~never taken: z-filtered rescan of the global run, same fold shape
                for (int j = 0; j < run; j += 4) {
                    int jj = j + grp;
                    if (jj < run) {
                        int2 rr = payl[s0 + jj];
                        if ((int)(((unsigned)rr.y) >> 25) == z) {
                            float w = __int_as_float(rr.x);
                            int p = rr.y;
                            unsigned hoff = ((unsigned)(p & 0x1FFFF) << 7) + sub8;
                            unsigned roff = ((((unsigned)p >> 17) & 0xFFu) << 8) + sub16;
                            uint2  hw = *(const uint2*) ((const char*)hWb  + hoff);
                            float4 rw = *(const float4*)((const char*)relW + roff);
                            ax += w * (__uint_as_float(hw.x << 16) + rw.x);
                            ay += w * (__uint_as_float(hw.x & 0xFFFF0000u) + rw.y);
                            az += w * (__uint_as_float(hw.y << 16) + rw.z);
                            aw += w * (__uint_as_float(hw.y & 0xFFFF0000u) + rw.w);
                            ws += w;
                        }
                    }
                }
            }
            // fold the 4 group-partials (group-uniform ws folds identically)
            ax += __shfl_xor(ax, 16); ax += __shfl_xor(ax, 32);
            ay += __shfl_xor(ay, 16); ay += __shfl_xor(ay, 32);
            az += __shfl_xor(az, 16); az += __shfl_xor(az, 32);
            aw += __shfl_xor(aw, 16); aw += __shfl_xor(aw, 32);
            ws += __shfl_xor(ws, 16); ws += __shfl_xor(ws, 32);
            if (grp == 0) {
                const float inv = 1.f / ws;     // ws > 0: every stored ex = exp(finite) > 0
                const float4 l4 = *(const float4*)(L + (long)i * D + sub * 4);
                float4 r;
                r.x = ax * inv + l4.x;
                r.y = ay * inv + l4.y;
                r.z = az * inv + l4.z;
                r.w = aw * inv + l4.w;
                *(float4*)(out + (long)i * D + sub * 4) = r;
            }
        } else {
            // cold: deg==0 (P=e^-16). out = h + h @ evolveW; evolveW is L2-hot.
            float hv = ldf(h, (long)i * D + lane, bf);
            float acc = hv;
            for (int k = 0; k < D; k++)
                acc += rl_f(hv, k) * ldf(evolveW, (long)k * D + lane, bf);
            out[(long)i * D + lane] = acc;
        }
    }
}

// safe diagnostic fallback
__global__ __launch_bounds__(256) void k_fallback(float* __restrict__ out) {
    int t = blockIdx.x * blockDim.x + threadIdx.x;
    if (t < N_NODES * D) out[t] = 0.f;
}

extern "C" void kernel_launch(void* const* d_in, const int* in_sizes, int n_in,
                              void* d_out, int out_size, void* d_ws, size_t ws_size,
                              hipStream_t stream) {
    const void* h       = d_in[0];
    const void* rel_emb = d_in[1];
    const void* wn      = d_in[2];
    const void* attn    = d_in[3];
    const void* delta   = d_in[4];
    const void* loopW   = d_in[5];
    const void* evolveW = d_in[6];
    const void* etime   = d_in[7];
    const int*  src     = (const int*)d_in[8];
    const int*  dst     = (const int*)d_in[9];
    const int*  etype   = (const int*)d_in[10];
    float* out = (float*)d_out;

    char* ws = (char*)d_ws;
    size_t off = 0;
    auto alloc = [&](size_t bytes) -> void* {
        off = (off + 255) & ~(size_t)255;
        void* p = ws + off;
        off += bytes;
        return p;
    };
    int2*  payl    = (int2*) alloc((size_t)N_EDGES * 8);       // 12.8 MB
    float* L       = (float*)alloc((size_t)N_NODES * D * 4);   // 25.6 MB
    bf16*  hWb     = (bf16*) alloc((size_t)N_NODES * D * 2);   // 12.8 MB
    float* relW    = (float*)alloc((size_t)N_RELS * D * 4);    // 51.2 KB
    float* s_src   = (float*)alloc((size_t)N_NODES * 4);       //  0.4 MB
    float* s_dst   = (float*)alloc((size_t)N_NODES * 4);       //  0.4 MB
    float* s_rel   = (float*)alloc((size_t)N_RELS * 4);        //  0.8 KB
    int*   bcnt    = (int*)  alloc((size_t)NBUCK * 4);
    int*   bbase   = (int*)  alloc((size_t)(NBUCK + 1) * 4);
    int*   bcursor = (int*)  alloc((size_t)NBUCK * 4);
    // total ~52.1 MB (< proven-available 52.9 MB from rounds 1-12)

    if (ws_size < off) {
        k_fallback<<<(N_NODES * D + 255) / 256, 256, 0, stream>>>(out);
        return;
    }

    hipMemsetAsync(bcnt, 0, (size_t)NBUCK * 4, stream);
    k_fused_proj<<<782, 512, 0, stream>>>(h, wn, attn, delta, rel_emb, dst,
                                          hWb, s_src, s_dst, relW, s_rel, bcnt);
    k_bscan<<<1, 1024, 0, stream>>>(bcnt, bbase, bcursor);
    k_bin<<<NBIN, 512, 0, stream>>>(s_src, s_dst, s_rel, etime, delta,
                                    src, dst, etype, bcursor, payl);
    k_loop<<<782, 512, 0, stream>>>(h, loopW, delta, L);
    k_bagg<<<NBUCK, 512, 0, stream>>>(payl, bbase, hWb, relW, h, evolveW, L, delta, out);
}

// Round 14
// 272.252 us; speedup vs baseline: 1.1363x; 1.0768x over previous
//
#include <hip/hip_runtime.h>
#include <hip/hip_bf16.h>

#define N_NODES 100000
#define N_EDGES 1600000
#define D       64
#define N_RELS  200
#define LEAKY   0.01f
// fine buckets of 128 nodes; z (d&127) packed into payl.y bits 25..31
#define NBUCK      782
#define BUCK_SHIFT 7
#define BUCK_MASK  127
#define NPB        128
#define CAP        3072            // LDS record capacity; mean 2048, sigma~45 -> 22 sigma
#define BIN_CHUNK  2048
#define NBIN       ((N_EDGES + BIN_CHUNK - 1) / BIN_CHUNK)   // 782
// LEDGER (measured): dense atomics (r12: padding hurt, WRITE +15MB); grid 782 for
// (512,4) matmuls (r9: 512 hurt); standalone matmul kernels (r10: merge spilled);
// (512,8) spills wreg kernels (r4). Round 14: MFMA for the dense GEMMs.

typedef __hip_bfloat16 bf16;
typedef __attribute__((ext_vector_type(8))) short bf16x8;
typedef __attribute__((ext_vector_type(4))) float f32x4;

__device__ __forceinline__ float b2f(bf16 x) { return __bfloat162float(x); }
__device__ __forceinline__ bf16  f2b(float x) { return __float2bfloat16(x); }

// header-independent bf16 bit helpers (RNE, finite inputs)
__device__ __forceinline__ unsigned short f2bs(float x) {
    unsigned u = __float_as_uint(x);
    unsigned r = (u + 0x7FFFu + ((u >> 16) & 1u)) >> 16;
    return (unsigned short)r;
}
__device__ __forceinline__ float bs2f(unsigned short s) {
    return __uint_as_float(((unsigned)s) << 16);
}

// dtype-dispatching float load: bf==1 -> storage is bf16, else f32 (probe says f32 here)
__device__ __forceinline__ float ldf(const void* p, long i, int bf) {
    return bf ? __bfloat162float(((const bf16*)p)[i]) : ((const float*)p)[i];
}
__device__ __forceinline__ int probe_bf(const void* delta) {
    return ((const unsigned short*)delta)[0] == 0x3F80 ? 1 : 0;
}

// uniform-index lane broadcast via v_readlane (result lands in SGPR)
__device__ __forceinline__ int rl_i(int v, int l) {
    return __builtin_amdgcn_readlane(v, l);
}
__device__ __forceinline__ float rl_f(float v, int l) {
    return __int_as_float(__builtin_amdgcn_readlane(__float_as_int(v), l));
}

// K1: node proj (hWb, s_src, s_dst) + rel proj (relW f32, s_rel) + coarse dst histogram.
// Phase A now MFMA (16x16x32 bf16): wave owns 16 nodes, one shot (6250 groups, 6256
// waves). Split-precision A (h = bf16 + bf16 residual, 2 MFMAs/product) keeps h
// near-f32 exact; only W's single-bf16 rounding (~0.005 abs) adds error.
// Layouts: A lane l -> row=l&15, k=(l>>4)*8+j (per half t: k+=t*32); B lane l ->
// col=l&15, k=(l>>4)*8+j; C/D (HW-verified m89): col=l&15, row=(l>>4)*4+reg.
// Scores computed exact-f32: per-lane dot8 vs a1/a2 slices + shfl_xor(16,32) fold.
__global__ __launch_bounds__(512, 4) void k_fused_proj(const void* __restrict__ h,
                                                       const void* __restrict__ wn,
                                                       const void* __restrict__ attn,
                                                       const void* __restrict__ delta,
                                                       const void* __restrict__ rel_emb,
                                                       const int* __restrict__ dst,
                                                       bf16* __restrict__ hWb,
                                                       float* __restrict__ s_src,
                                                       float* __restrict__ s_dst,
                                                       float* __restrict__ relW,
                                                       float* __restrict__ s_rel,
                                                       int* __restrict__ bcnt) {
    __shared__ int bh[NBUCK];
    const int bf = probe_bf(delta);
    const int wave = threadIdx.x >> 6;
    const int lane = threadIdx.x & 63;
    const int gw = blockIdx.x * 8 + wave;
    const int nwaves = gridDim.x * 8;
    const int rc16 = lane & 15;          // A-row / C-col index
    const int kg   = lane >> 4;          // k-group
    // phase A: one 16-node group per wave via MFMA
    {
        const int base = gw * 16;        // N_NODES % 16 == 0; 6250 groups
        if (base < N_NODES) {
            bf16x8 Bf[4][2];
            #pragma unroll
            for (int c = 0; c < 4; c++)
                #pragma unroll
                for (int t = 0; t < 2; t++)
                    #pragma unroll
                    for (int j = 0; j < 8; j++)
                        Bf[c][t][j] = (short)f2bs(ldf(wn, (long)(t * 32 + kg * 8 + j) * D + c * 16 + rc16, bf));
            bf16x8 Ahi[2], Alo[2];
            float p1 = 0.f, p2 = 0.f;
            #pragma unroll
            for (int t = 0; t < 2; t++) {
                #pragma unroll
                for (int j = 0; j < 8; j++) {
                    float hv = ldf(h, (long)(base + rc16) * D + t * 32 + kg * 8 + j, bf);
                    p1 += hv * ldf(attn, t * 32 + kg * 8 + j, bf);
                    p2 += hv * ldf(attn, D + t * 32 + kg * 8 + j, bf);
                    unsigned short hi = f2bs(hv);
                    Ahi[t][j] = (short)hi;
                    Alo[t][j] = (short)f2bs(hv - bs2f(hi));
                }
            }
            p1 += __shfl_xor(p1, 16); p1 += __shfl_xor(p1, 32);
            p2 += __shfl_xor(p2, 16); p2 += __shfl_xor(p2, 32);
            if (lane < 16) { s_src[base + rc16] = p1; s_dst[base + rc16] = p2; }
            f32x4 acc[4];
            #pragma unroll
            for (int c = 0; c < 4; c++) acc[c] = (f32x4){0.f, 0.f, 0.f, 0.f};
            #pragma unroll
            for (int t = 0; t < 2; t++)
                #pragma unroll
                for (int c = 0; c < 4; c++) {
                    acc[c] = __builtin_amdgcn_mfma_f32_16x16x32_bf16(Ahi[t], Bf[c][t], acc[c], 0, 0, 0);
                    acc[c] = __builtin_amdgcn_mfma_f32_16x16x32_bf16(Alo[t], Bf[c][t], acc[c], 0, 0, 0);
                }
            #pragma unroll
            for (int c = 0; c < 4; c++)
                #pragma unroll
                for (int r = 0; r < 4; r++)
                    hWb[(long)(base + kg * 4 + r) * D + c * 16 + rc16] = f2b(acc[c][r]);
        }
    }
    // phase B: relations (200 waves; L2-hot, tiny) — unchanged readlane form
    const float a3 = ldf(attn, 2 * D + lane, bf);
    for (int r = gw; r < N_RELS; r += nwaves) {
        float rv = ldf(rel_emb, (long)r * D + lane, bf);
        float p3 = rv * a3;
        #pragma unroll
        for (int off = 32; off; off >>= 1) p3 += __shfl_xor(p3, off);
        if (lane == 0) s_rel[r] = p3;
        float acc = 0.f;
        #pragma unroll
        for (int k = 0; k < D; k++) {
            acc += rl_f(rv, k) * ldf(wn, (long)(D + k) * D + lane, bf);
        }
        relW[r * D + lane] = acc;
    }
    // phase C: coarse (dst>>7) histogram, LDS-aggregated; dense flush (r12 lesson)
    for (int t = threadIdx.x; t < NBUCK; t += 512) bh[t] = 0;
    __syncthreads();
    for (int t = blockIdx.x * 512 + threadIdx.x; t < N_EDGES; t += gridDim.x * 512)
        atomicAdd(&bh[dst[t] >> BUCK_SHIFT], 1);
    __syncthreads();
    for (int t = threadIdx.x; t < NBUCK; t += 512) {
        int v = bh[t];
        if (v) atomicAdd(&bcnt[t], v);
    }
}

// exclusive scan of the 782 bucket counts; primes bcursor and bbase
__global__ __launch_bounds__(1024) void k_bscan(const int* __restrict__ bcnt,
                                                int* __restrict__ bbase,
                                                int* __restrict__ bcursor) {
    __shared__ int s[1024];
    const int tid = threadIdx.x;
    int v = (tid < NBUCK) ? bcnt[tid] : 0;
    s[tid] = v;
    __syncthreads();
    for (int off = 1; off < 1024; off <<= 1) {
        int t = (tid >= off) ? s[tid - off] : 0;
        __syncthreads();
        s[tid] += t;
        __syncthreads();
    }
    if (tid < NBUCK) {
        int e = s[tid] - v;
        bbase[tid] = e;
        bcursor[tid] = e;
    }
    if (tid == 1023) bbase[NBUCK] = s[1023];   // == N_EDGES
}

// Pass B: rank edges into 782 fine buckets via LDS atomics, then scatter
// {ex, src | rel<<17 | z<<25} (8B) into per-(block,bucket) runs.
// 782 blocks at (512,6) -> 3 blocks/CU resident. Dense cursor atomics.
__global__ __launch_bounds__(512, 6) void k_bin(const float* __restrict__ s_src,
                                                const float* __restrict__ s_dst,
                                                const float* __restrict__ s_rel,
                                                const void* __restrict__ etime,
                                                const void* __restrict__ delta,
                                                const int* __restrict__ src,
                                                const int* __restrict__ dst,
                                                const int* __restrict__ etype,
                                                int* __restrict__ bcursor,
                                                int2* __restrict__ payl) {
    __shared__ int lh[NBUCK];
    __shared__ int gbase[NBUCK];
    const int bf = probe_bf(delta);
    const float df = ldf(delta, 0, bf);
    const int tid = threadIdx.x;
    const int base = blockIdx.x * BIN_CHUNK;
    for (int t = tid; t < NBUCK; t += 512) lh[t] = 0;
    __syncthreads();
    int2 rc[4];
    int rk[4], bk[4];
    #pragma unroll
    for (int j = 0; j < 4; j++) {
        int e = base + j * 512 + tid;
        bk[j] = -1;
        if (e < N_EDGES) {
            int s = src[e], d = dst[e], r = etype[e];
            float scv = s_src[s] + s_dst[d] + s_rel[r];
            float lre = scv > 0.f ? scv : LEAKY * scv;
            float score = (-ldf(etime, e, bf) * df) * lre;
            rc[j].x = __float_as_int(__expf(score));
            rc[j].y = s | (r << 17) | ((d & BUCK_MASK) << 25);  // 17+8+7 = 32 bits
            int b = d >> BUCK_SHIFT;
            bk[j] = b;
            rk[j] = atomicAdd(&lh[b], 1);
        }
    }
    __syncthreads();
    for (int t = tid; t < NBUCK; t += 512) {
        int v = lh[t];
        if (v) gbase[t] = atomicAdd(&bcursor[t], v);
    }
    __syncthreads();
    #pragma unroll
    for (int j = 0; j < 4; j++) {
        if (bk[j] >= 0) payl[gbase[bk[j]] + rk[j]] = rc[j];
    }
}

// Dense loop-term: L[i] = h[i] @ loopW via MFMA, same template as proj phase A
// (split-precision A, f32 output -> no output quantization). One 16-node group
// per wave; standalone kernel (r10 lesson: do not merge).
__global__ __launch_bounds__(512, 4) void k_loop(const void* __restrict__ h,
                                                 const void* __restrict__ loopW,
                                                 const void* __restrict__ delta,
                                                 float* __restrict__ L) {
    const int bf = probe_bf(delta);
    const int wave = threadIdx.x >> 6;
    const int lane = threadIdx.x & 63;
    const int gw = blockIdx.x * 8 + wave;
    const int rc16 = lane & 15;
    const int kg   = lane >> 4;
    const int base = gw * 16;
    if (base >= N_NODES) return;
    bf16x8 Bf[4][2];
    #pragma unroll
    for (int c = 0; c < 4; c++)
        #pragma unroll
        for (int t = 0; t < 2; t++)
            #pragma unroll
            for (int j = 0; j < 8; j++)
                Bf[c][t][j] = (short)f2bs(ldf(loopW, (long)(t * 32 + kg * 8 + j) * D + c * 16 + rc16, bf));
    bf16x8 Ahi[2], Alo[2];
    #pragma unroll
    for (int t = 0; t < 2; t++)
        #pragma unroll
        for (int j = 0; j < 8; j++) {
            float hv = ldf(h, (long)(base + rc16) * D + t * 32 + kg * 8 + j, bf);
            unsigned short hi = f2bs(hv);
            Ahi[t][j] = (short)hi;
            Alo[t][j] = (short)f2bs(hv - bs2f(hi));
        }
    f32x4 acc[4];
    #pragma unroll
    for (int c = 0; c < 4; c++) acc[c] = (f32x4){0.f, 0.f, 0.f, 0.f};
    #pragma unroll
    for (int t = 0; t < 2; t++)
        #pragma unroll
        for (int c = 0; c < 4; c++) {
            acc[c] = __builtin_amdgcn_mfma_f32_16x16x32_bf16(Ahi[t], Bf[c][t], acc[c], 0, 0, 0);
            acc[c] = __builtin_amdgcn_mfma_f32_16x16x32_bf16(Alo[t], Bf[c][t], acc[c], 0, 0, 0);
        }
    #pragma unroll
    for (int c = 0; c < 4; c++)
        #pragma unroll
        for (int r = 0; r < 4; r++)
            L[(long)(base + kg * 4 + r) * D + c * 16 + rc16] = acc[c][r];
}

// Fused bucket-sort + aggregate: one block per 128-node bucket. Sort the bucket's
// edge run into LDS, then aggregate directly from LDS with group-broadcast reads.
// (512,6): LDS 25.6KB*3=77KB fits, VGPR cap 85 -> 3 blocks/CU resident.
__global__ __launch_bounds__(512, 6) void k_bagg(const int2* __restrict__ payl,
                                                 const int* __restrict__ bbase,
                                                 const bf16* __restrict__ hWb,
                                                 const float* __restrict__ relW,
                                                 const void* __restrict__ h,
                                                 const void* __restrict__ evolveW,
                                                 const float* __restrict__ L,
                                                 const void* __restrict__ delta,
                                                 float* __restrict__ out) {
    __shared__ int2 recs[CAP];              // 24 KB
    __shared__ int cnt[NPB], off[NPB], fc[NPB];
    const int bf = probe_bf(delta);
    const int tid = threadIdx.x;
    const int b = blockIdx.x;
    const int n0 = b << BUCK_SHIFT;
    const int s0 = bbase[b], s1 = bbase[b + 1];
    const int run = s1 - s0;
    if (tid < NPB) { cnt[tid] = 0; fc[tid] = 0; }
    __syncthreads();
    // fine histogram over the run
    for (int i = tid; i < run; i += 512)
        atomicAdd(&cnt[((unsigned)payl[s0 + i].y) >> 25], 1);
    __syncthreads();
    if (tid < NPB) off[tid] = cnt[tid];
    __syncthreads();
    for (int o = 1; o < NPB; o <<= 1) {
        int t = 0;
        if (tid < NPB && tid >= o) t = off[tid - o];
        __syncthreads();
        if (tid < NPB) off[tid] += t;
        __syncthreads();
    }
    if (tid < NPB) off[tid] -= cnt[tid];    // exclusive offsets
    __syncthreads();
    // scatter into LDS (payl re-read is L2-hot)
    for (int i = tid; i < run; i += 512) {
        int2 r = payl[s0 + i];
        int z = ((unsigned)r.y) >> 25;
        int pos = off[z] + atomicAdd(&fc[z], 1);
        if (pos < CAP) recs[pos] = r;
    }
    __syncthreads();
    // aggregation: 8 waves x 16 nodes, 4-group x 16-lane x 4-channel gather
    const int wave = tid >> 6, lane = tid & 63;
    const int grp = lane >> 4, sub = lane & 15;
    const unsigned sub8 = (unsigned)sub << 3;
    const unsigned sub16 = (unsigned)sub << 4;
    for (int t = 0; t < 16; ++t) {
        const int z = wave * 16 + t;
        const int i = n0 + z;
        if (i >= N_NODES) break;
        const int d = cnt[z], o = off[z];
        if (d > 0) {
            float ax = 0.f, ay = 0.f, az = 0.f, aw = 0.f, ws = 0.f;
            if (o + d <= CAP) {
                #pragma unroll 2
                for (int j = 0; j < d; j += 4) {
                    int jj = j + grp;
                    int2 rr = (jj < d) ? recs[o + jj] : make_int2(0, 0);  // LDS broadcast in group
                    float w = __int_as_float(rr.x);                        // 0.0 when masked
                    int p = rr.y;
                    unsigned hoff = ((unsigned)(p & 0x1FFFF) << 7) + sub8;
                    unsigned roff = ((((unsigned)p >> 17) & 0xFFu) << 8) + sub16;
                    uint2  hw = *(const uint2*) ((const char*)hWb  + hoff);
                    float4 rw = *(const float4*)((const char*)relW + roff);
                    float f0 = __uint_as_float(hw.x << 16);
                    float f1 = __uint_as_float(hw.x & 0xFFFF0000u);
                    float f2 = __uint_as_float(hw.y << 16);
                    float f3 = __uint_as_float(hw.y & 0xFFFF0000u);
                    ax += w * (f0 + rw.x);
                    ay += w * (f1 + rw.y);
                    az += w * (f2 + rw.z);
                    aw += w * (f3 + rw.w);
                    ws += w;
                }
            } else {
                // ~never taken: z-filtered rescan of the global run, same fold shape
                for (int j = 0; j < run; j += 4) {
                    int jj = j + grp;
                    if (jj < run) {
                        int2 rr = payl[s0 + jj];
                        if ((int)(((unsigned)rr.y) >> 25) == z) {
                            float w = __int_as_float(rr.x);
                            int p = rr.y;
                            unsigned hoff = ((unsigned)(p & 0x1FFFF) << 7) + sub8;
                            unsigned roff = ((((unsigned)p >> 17) & 0xFFu) << 8) + sub16;
                            uint2  hw = *(const uint2*) ((const char*)hWb  + hoff);
                            float4 rw = *(const float4*)((const char*)relW + roff);
                            ax += w * (__uint_as_float(hw.x << 16) + rw.x);
                            ay += w * (__uint_as_float(hw.x & 0xFFFF0000u) + rw.y);
                            az += w * (__uint_as_float(hw.y << 16) + rw.z);
                            aw += w * (__uint_as_float(hw.y & 0xFFFF0000u) + rw.w);
                            ws += w;
                        }
                    }
                }
            }
            // fold the 4 group-partials (group-uniform ws folds identically)
            ax += __shfl_xor(ax, 16); ax += __shfl_xor(ax, 32);
            ay += __shfl_xor(ay, 16); ay += __shfl_xor(ay, 32);
            az += __shfl_xor(az, 16); az += __shfl_xor(az, 32);
            aw += __shfl_xor(aw, 16); aw += __shfl_xor(aw, 32);
            ws += __shfl_xor(ws, 16); ws += __shfl_xor(ws, 32);
            if (grp == 0) {
                const float inv = 1.f / ws;     // ws > 0: every stored ex = exp(finite) > 0
                const float4 l4 = *(const float4*)(L + (long)i * D + sub * 4);
                float4 r;
                r.x = ax * inv + l4.x;
                r.y = ay * inv + l4.y;
                r.z = az * inv + l4.z;
                r.w = aw * inv + l4.w;
                *(float4*)(out + (long)i * D + sub * 4) = r;
            }
        } else {
            // cold: deg==0 (P=e^-16). out = h + h @ evolveW; evolveW is L2-hot.
            float hv = ldf(h, (long)i * D + lane, bf);
            float acc = hv;
            for (int k = 0; k < D; k++)
                acc += rl_f(hv, k) * ldf(evolveW, (long)k * D + lane, bf);
            out[(long)i * D + lane] = acc;
        }
    }
}

// safe diagnostic fallback
__global__ __launch_bounds__(256) void k_fallback(float* __restrict__ out) {
    int t = blockIdx.x * blockDim.x + threadIdx.x;
    if (t < N_NODES * D) out[t] = 0.f;
}

extern "C" void kernel_launch(void* const* d_in, const int* in_sizes, int n_in,
                              void* d_out, int out_size, void* d_ws, size_t ws_size,
                              hipStream_t stream) {
    const void* h       = d_in[0];
    const void* rel_emb = d_in[1];
    const void* wn      = d_in[2];
    const void* attn    = d_in[3];
    const void* delta   = d_in[4];
    const void* loopW   = d_in[5];
    const void* evolveW = d_in[6];
    const void* etime   = d_in[7];
    const int*  src     = (const int*)d_in[8];
    const int*  dst     = (const int*)d_in[9];
    const int*  etype   = (const int*)d_in[10];
    float* out = (float*)d_out;

    char* ws = (char*)d_ws;
    size_t off = 0;
    auto alloc = [&](size_t bytes) -> void* {
        off = (off + 255) & ~(size_t)255;
        void* p = ws + off;
        off += bytes;
        return p;
    };
    int2*  payl    = (int2*) alloc((size_t)N_EDGES * 8);       // 12.8 MB
    float* L       = (float*)alloc((size_t)N_NODES * D * 4);   // 25.6 MB
    bf16*  hWb     = (bf16*) alloc((size_t)N_NODES * D * 2);   // 12.8 MB
    float* relW    = (float*)alloc((size_t)N_RELS * D * 4);    // 51.2 KB
    float* s_src   = (float*)alloc((size_t)N_NODES * 4);       //  0.4 MB
    float* s_dst   = (float*)alloc((size_t)N_NODES * 4);       //  0.4 MB
    float* s_rel   = (float*)alloc((size_t)N_RELS * 4);        //  0.8 KB
    int*   bcnt    = (int*)  alloc((size_t)NBUCK * 4);
    int*   bbase   = (int*)  alloc((size_t)(NBUCK + 1) * 4);
    int*   bcursor = (int*)  alloc((size_t)NBUCK * 4);
    // total ~52.1 MB (< proven-available 52.9 MB from rounds 1-13)

    if (ws_size < off) {
        k_fallback<<<(N_NODES * D + 255) / 256, 256, 0, stream>>>(out);
        return;
    }

    hipMemsetAsync(bcnt, 0, (size_t)NBUCK * 4, stream);
    k_fused_proj<<<782, 512, 0, stream>>>(h, wn, attn, delta, rel_emb, dst,
                                          hWb, s_src, s_dst, relW, s_rel, bcnt);
    k_bscan<<<1, 1024, 0, stream>>>(bcnt, bbase, bcursor);
    k_bin<<<NBIN, 512, 0, stream>>>(s_src, s_dst, s_rel, etime, delta,
                                    src, dst, etype, bcursor, payl);
    k_loop<<<782, 512, 0, stream>>>(h, loopW, delta, L);
    k_bagg<<<NBUCK, 512, 0, stream>>>(payl, bbase, hWb, relW, h, evolveW, L, delta, out);
}